// Round 2
// baseline (98.423 us; speedup 1.0000x reference)
//
#include <hip/hip_runtime.h>
#include <math.h>

#define N_FFT 16384
#define MVAL 64
#define ROWS 1024   // B*Cin = B*Cout = 16*64

// ---------------- ws layout (float offsets) ----------------
#define OFF_TAB  0
#define OFF_CASA 16384
#define OFF_CASB 1064960
#define OFF_PART 2113536      // [64][1024][64]
#define OFF_XH   6307840      // [1024][64]
#define OFF_LOWT 6373376      // [64][1024]

__global__ __launch_bounds__(256) void k_tab(float* __restrict__ castab) {
    int i = blockIdx.x * 256 + threadIdx.x;
    if (i < N_FFT) {
        double ang = 6.283185307179586476925287 * (double)i / (double)N_FFT;
        castab[i] = (float)(cos(ang) + sin(ang));
    }
}

__global__ __launch_bounds__(256) void k_fill(const float* __restrict__ castab,
                                              float* __restrict__ casA,
                                              float* __restrict__ casB) {
    int tid = blockIdx.x * 256 + threadIdx.x;   // 0 .. 2*2^20-1
    if (tid < (1 << 20)) {
        int n = tid >> 6, m = tid & 63;
        casA[tid] = castab[(n * m) & (N_FFT - 1)];
    } else {
        int t2 = tid - (1 << 20);
        int m = t2 >> 14, n = t2 & (N_FFT - 1);
        casB[t2] = castab[(m * n) & (N_FFT - 1)];
    }
}

// Step A: partial[ks][r][m] = sum_{k in split ks} x[r][k] * casA[k][m]
// grid 2048 = 64 ksplits * 32 rowblocks; block 256 = 16 rg * 16 mg
// LDS: xs 32x64 XOR-swizzled (conflict-free b128), cs 64x64 linear. 24 KB.
__global__ __launch_bounds__(256) void kA(const float* __restrict__ x,
                                          const float* __restrict__ casA,
                                          float* __restrict__ partial) {
    const int rb = blockIdx.x & 31;
    const int ks = blockIdx.x >> 5;
    const int rowbase = rb * 32;
    const int k0base = ks * 256;

    __shared__ float xs[32 * 64];   // word r*64 + 4*(q^(r&15)) + u  holds x[r][k0+4q+u]
    __shared__ float cs[64 * 64];   // [k][m] linear

    const int t  = threadIdx.x;
    const int rg = t & 15;          // rows rg, rg+16
    const int mg = t >> 4;          // m = mg*4 .. +3

    float acc0[4] = {0.f, 0.f, 0.f, 0.f};
    float acc1[4] = {0.f, 0.f, 0.f, 0.f};

    for (int kc = 0; kc < 4; ++kc) {
        const int k0 = k0base + kc * 64;
        if (kc) __syncthreads();
        // stage xs: 32 rows x 64 k = 512 float4, swizzled column blocks
#pragma unroll
        for (int it = 0; it < 2; ++it) {
            int f = it * 256 + t;
            int r = f >> 4, q = f & 15;
            const float4 v = *reinterpret_cast<const float4*>(
                &x[(size_t)(rowbase + r) * N_FFT + k0 + q * 4]);
            *reinterpret_cast<float4*>(&xs[r * 64 + ((q ^ (r & 15)) << 2)]) = v;
        }
        // stage cs: casA rows k0..k0+63 are one contiguous 16 KB block
#pragma unroll
        for (int it = 0; it < 4; ++it) {
            int f = it * 256 + t;
            *reinterpret_cast<float4*>(&cs[f * 4]) =
                *reinterpret_cast<const float4*>(&casA[(size_t)k0 * 64 + f * 4]);
        }
        __syncthreads();

#pragma unroll 4
        for (int Q = 0; Q < 16; ++Q) {
            const int col = ((Q ^ rg) << 2);
            const float4 xa = *reinterpret_cast<const float4*>(&xs[rg * 64 + col]);
            const float4 xb = *reinterpret_cast<const float4*>(&xs[(rg + 16) * 64 + col]);
            const float xav[4] = {xa.x, xa.y, xa.z, xa.w};
            const float xbv[4] = {xb.x, xb.y, xb.z, xb.w};
#pragma unroll
            for (int u = 0; u < 4; ++u) {
                const float4 c = *reinterpret_cast<const float4*>(
                    &cs[(Q * 4 + u) * 64 + mg * 4]);
                acc0[0] = fmaf(xav[u], c.x, acc0[0]);
                acc0[1] = fmaf(xav[u], c.y, acc0[1]);
                acc0[2] = fmaf(xav[u], c.z, acc0[2]);
                acc0[3] = fmaf(xav[u], c.w, acc0[3]);
                acc1[0] = fmaf(xbv[u], c.x, acc1[0]);
                acc1[1] = fmaf(xbv[u], c.y, acc1[1]);
                acc1[2] = fmaf(xbv[u], c.z, acc1[2]);
                acc1[3] = fmaf(xbv[u], c.w, acc1[3]);
            }
        }
    }

    const size_t base = ((size_t)(ks << 10) + rowbase + rg) * 64 + mg * 4;
    *reinterpret_cast<float4*>(&partial[base]) =
        make_float4(acc0[0], acc0[1], acc0[2], acc0[3]);
    *reinterpret_cast<float4*>(&partial[base + 16 * 64]) =
        make_float4(acc1[0], acc1[1], acc1[2], acc1[3]);
}

// reduce 64 partials -> xh; grid 256 x 256 threads, one float per thread
__global__ __launch_bounds__(256) void kR(const float* __restrict__ partial,
                                          float* __restrict__ xh) {
    const int idx = blockIdx.x * 256 + threadIdx.x;   // 0..65535
    float a0 = 0.f, a1 = 0.f, a2 = 0.f, a3 = 0.f;
#pragma unroll 4
    for (int sp = 0; sp < 64; sp += 4) {
        a0 += partial[((size_t)(sp + 0) << 16) + idx];
        a1 += partial[((size_t)(sp + 1) << 16) + idx];
        a2 += partial[((size_t)(sp + 2) << 16) + idx];
        a3 += partial[((size_t)(sp + 3) << 16) + idx];
    }
    xh[idx] = (a0 + a1) + (a2 + a3);
}

// Step B: lowT[m][b*64+o] = sum_i xh[b*64+i][m] * w[(o*64+i)*64+m]
// grid 256 = 16 b * 16 og; block 256 = 4 o * 64 m
__global__ __launch_bounds__(256) void kB(const float* __restrict__ xh,
                                          const float* __restrict__ w,
                                          float* __restrict__ lowT) {
    const int b  = blockIdx.x >> 4;
    const int og = blockIdx.x & 15;
    const int o  = og * 4 + (threadIdx.x >> 6);
    const int m  = threadIdx.x & 63;
    float a0 = 0.f, a1 = 0.f, a2 = 0.f, a3 = 0.f;
#pragma unroll 4
    for (int i = 0; i < 64; i += 4) {
        a0 = fmaf(xh[(size_t)((b * 64 + i + 0) << 6) + m], w[(size_t)((o * 64 + i + 0) << 6) + m], a0);
        a1 = fmaf(xh[(size_t)((b * 64 + i + 1) << 6) + m], w[(size_t)((o * 64 + i + 1) << 6) + m], a1);
        a2 = fmaf(xh[(size_t)((b * 64 + i + 2) << 6) + m], w[(size_t)((o * 64 + i + 2) << 6) + m], a2);
        a3 = fmaf(xh[(size_t)((b * 64 + i + 3) << 6) + m], w[(size_t)((o * 64 + i + 3) << 6) + m], a3);
    }
    lowT[(size_t)m * ROWS + b * 64 + o] = (a0 + a1) + (a2 + a3);
}

// Step C: out[r][n] = (1/N) * sum_m lowT[m][r] * casB[m][n]
// grid 4096 = 256 nb * 16 rb; block 256 = 16 rg * 16 ng; tile 64r x 64n
// LDS 32 KB staged once (K=64, no chunk loop).
__global__ __launch_bounds__(256) void kC(const float* __restrict__ lowT,
                                          const float* __restrict__ casB,
                                          float* __restrict__ out) {
    const int nb = blockIdx.x >> 4;
    const int rb = blockIdx.x & 15;
    const int rowbase = rb * 64;
    const int n0 = nb * 64;

    __shared__ float lsd[64 * 64];    // [m][r]
    __shared__ float csb[64 * 64];    // [m][n]

    const int t  = threadIdx.x;
    const int rg = t >> 4;            // rows rg*4 .. +3
    const int ng = t & 15;            // cols ng*4 .. +3

#pragma unroll
    for (int it = 0; it < 4; ++it) {
        int f = it * 256 + t;
        int m = f >> 4, u = f & 15;
        *reinterpret_cast<float4*>(&lsd[m * 64 + u * 4]) =
            *reinterpret_cast<const float4*>(&lowT[(size_t)m * ROWS + rowbase + u * 4]);
        *reinterpret_cast<float4*>(&csb[m * 64 + u * 4]) =
            *reinterpret_cast<const float4*>(&casB[(size_t)m * N_FFT + n0 + u * 4]);
    }
    __syncthreads();

    float acc[4][4];
#pragma unroll
    for (int j = 0; j < 4; ++j)
#pragma unroll
        for (int q = 0; q < 4; ++q) acc[j][q] = 0.f;

#pragma unroll 4
    for (int kk = 0; kk < 64; ++kk) {
        const float4 l = *reinterpret_cast<const float4*>(&lsd[kk * 64 + rg * 4]);
        const float4 c = *reinterpret_cast<const float4*>(&csb[kk * 64 + ng * 4]);
        const float lv[4] = {l.x, l.y, l.z, l.w};
#pragma unroll
        for (int j = 0; j < 4; ++j) {
            acc[j][0] = fmaf(lv[j], c.x, acc[j][0]);
            acc[j][1] = fmaf(lv[j], c.y, acc[j][1]);
            acc[j][2] = fmaf(lv[j], c.z, acc[j][2]);
            acc[j][3] = fmaf(lv[j], c.w, acc[j][3]);
        }
    }

    const float sc = 1.0f / (float)N_FFT;
#pragma unroll
    for (int j = 0; j < 4; ++j) {
        const size_t row = (size_t)rowbase + rg * 4 + j;
        *reinterpret_cast<float4*>(&out[row * N_FFT + n0 + ng * 4]) =
            make_float4(acc[j][0] * sc, acc[j][1] * sc, acc[j][2] * sc, acc[j][3] * sc);
    }
}

extern "C" void kernel_launch(void* const* d_in, const int* in_sizes, int n_in,
                              void* d_out, int out_size, void* d_ws, size_t ws_size,
                              hipStream_t stream) {
    const float* x = (const float*)d_in[0];
    const float* w = (const float*)d_in[1];
    float* out = (float*)d_out;
    float* ws  = (float*)d_ws;

    float* castab  = ws + OFF_TAB;
    float* casA    = ws + OFF_CASA;
    float* casB    = ws + OFF_CASB;
    float* partial = ws + OFF_PART;
    float* xh      = ws + OFF_XH;
    float* lowT    = ws + OFF_LOWT;

    k_tab<<<64, 256, 0, stream>>>(castab);
    k_fill<<<8192, 256, 0, stream>>>(castab, casA, casB);
    kA<<<2048, 256, 0, stream>>>(x, casA, partial);
    kR<<<256, 256, 0, stream>>>(partial, xh);
    kB<<<256, 256, 0, stream>>>(xh, w, lowT);
    kC<<<4096, 256, 0, stream>>>(lowT, casB, out);
}